// Round 4
// baseline (94.852 us; speedup 1.0000x reference)
//
#include <hip/hip_runtime.h>

// 4-qubit, 2-layer QML circuit, B=1M samples.
// FOUR samples per thread, processed SEQUENTIALLY (not interleaved — round 2
// proved interleaving blows VGPRs). Grid-stride sample mapping keeps every
// load/store perfectly coalesced. 262144 threads = 1024 blocks = 4 waves/SIMD:
// the whole batch is one fully-resident wave generation, amortizing per-wave
// launch/drain/load-latency overheads 4x (the theory for why qml sits at ~3x
// its VALU-issue floor: 16384 short-lived waves dominated by fixed per-wave
// costs, not by the compute body — instruction cuts in R1..R3 moved nothing).
//
// Algebra (harness-validated in round 3):
//  - layer-2 RZ gates dead (diagonal; killed by CNOT permutation + |.|^2)
//  - qubit-3 layer-2 gate folded into the observables:
//    M3 = U3' Z U3 = m*Z + u*X + v*Y, m = cos(wy3)cos(x3), u = -sin(wy3),
//    v = cos(wy3)sin(x3). Per q3-pair (a0,a1) after q0,q1,q2 butterflies:
//      S = |a0|^2+|a1|^2
//      D = m*(|a0|^2-|a1|^2) + 2u*Re(conj(a0)a1) + 2v*Im(conj(a0)a1)
//    z0..z2 = signed sums of S, z3 = signed sum of D (prefix-Z parities).
//
// Flat amp index n = q0*8 + q1*4 + q2*2 + q3 (qubit 0 = bit 3).
// Trig: x in [0,2pi) -> sin(x/2) = v_sin(x * 1/(4pi)), no range reduction.

struct C2 { float r, i; };

__device__ __forceinline__ C2 cmul(C2 a, C2 b) {
    C2 o;
    o.r = a.r * b.r - a.i * b.i;
    o.i = a.r * b.i + a.i * b.r;
    return o;
}

#define INV_4PI 0.07957747154594767f

// ---- precompute weight-only gate constants (44 floats) ----
// g[0..31]:  l=0 qubit q: g[q*8 + 0..7] = Pr,Pi,Qr,Qi,Rr,Ri,Sr,Si
// g[32..37]: l=1 qubit q<3: cos(wy/2), sin(wy/2)
// g[40..42]: l=1 qubit 3 (M-operator): cos(wy3), -2*sin(wy3), 4*cos(wy3)
__global__ void precompute_gates(const float* __restrict__ w, float* __restrict__ g) {
    int t = threadIdx.x;  // 0..7 -> l*4 + q
    if (t >= 8) return;
    int l = t >> 2, q = t & 3;
    if (l == 0) {
        float thy = w[q * 2 + 0];
        float thz = w[q * 2 + 1];
        float cy = cosf(0.5f * thy), sy = sinf(0.5f * thy);
        float cz = cosf(0.5f * thz), sz = sinf(0.5f * thz);
        float* o = g + q * 8;
        o[0] = cz * cy;  o[1] = -sz * cy;
        o[2] = sz * sy;  o[3] =  cz * sy;
        o[4] = cz * sy;  o[5] =  sz * sy;
        o[6] = sz * cy;  o[7] = -cz * cy;
    } else if (q < 3) {
        float thy = w[8 + q * 2 + 0];  // layer-2 RZ params are dead
        g[32 + q * 2 + 0] = cosf(0.5f * thy);
        g[32 + q * 2 + 1] = sinf(0.5f * thy);
    } else {
        float thy = w[8 + 3 * 2 + 0];  // qubit 3: full-angle M constants
        g[40] =  cosf(thy);
        g[41] = -2.0f * sinf(thy);
        g[42] =  4.0f * cosf(thy);
    }
}

__device__ __forceinline__ void cnot_chain(C2 st[16]) {
    // CNOT(0,1): q0=1 -> flip q1: swap n=8..11 <-> 12..15
    #pragma unroll
    for (int j = 0; j < 4; j++) { C2 t = st[8 + j]; st[8 + j] = st[12 + j]; st[12 + j] = t; }
    // CNOT(1,2): q1=1 -> flip q2
    {
        C2 t;
        t = st[4];  st[4]  = st[6];  st[6]  = t;
        t = st[5];  st[5]  = st[7];  st[7]  = t;
        t = st[12]; st[12] = st[14]; st[14] = t;
        t = st[13]; st[13] = st[15]; st[15] = t;
    }
    // CNOT(2,3): q2=1 -> flip q3
    {
        C2 t;
        t = st[2];  st[2]  = st[3];  st[3]  = t;
        t = st[6];  st[6]  = st[7];  st[7]  = t;
        t = st[10]; st[10] = st[11]; st[11] = t;
        t = st[14]; st[14] = st[15]; st[15] = t;
    }
}

__device__ __forceinline__ float4 sample_out(float4 xv, const float* __restrict__ g) {
    float c[4], s[4];
    {
        float r0 = xv.x * INV_4PI, r1 = xv.y * INV_4PI;
        float r2 = xv.z * INV_4PI, r3 = xv.w * INV_4PI;
        s[0] = __builtin_amdgcn_sinf(r0); c[0] = __builtin_amdgcn_cosf(r0);
        s[1] = __builtin_amdgcn_sinf(r1); c[1] = __builtin_amdgcn_cosf(r1);
        s[2] = __builtin_amdgcn_sinf(r2); c[2] = __builtin_amdgcn_cosf(r2);
        s[3] = __builtin_amdgcn_sinf(r3); c[3] = __builtin_amdgcn_cosf(r3);
    }

    // ---- layer 1: product state, per-qubit 2-vectors (table -> s_loads) ----
    C2 v[4][2];
    #pragma unroll
    for (int q = 0; q < 4; q++) {
        const float* o = g + q * 8;
        v[q][0].r = c[q] * o[0] + s[q] * o[2];
        v[q][0].i = c[q] * o[1] + s[q] * o[3];
        v[q][1].r = c[q] * o[4] + s[q] * o[6];
        v[q][1].i = c[q] * o[5] + s[q] * o[7];
    }

    // ---- tensor expansion to 16 amps ----
    C2 t01[4], t23[4], st[16];
    #pragma unroll
    for (int a = 0; a < 2; a++)
        #pragma unroll
        for (int b = 0; b < 2; b++) {
            t01[a * 2 + b] = cmul(v[0][a], v[1][b]);
            t23[a * 2 + b] = cmul(v[2][a], v[3][b]);
        }
    #pragma unroll
    for (int a = 0; a < 4; a++)
        #pragma unroll
        for (int b = 0; b < 4; b++)
            st[a * 4 + b] = cmul(t01[a], t23[b]);

    cnot_chain(st);

    // ---- layer 2: SU(2) = RY(wy)*RX(x) butterflies, qubits 0..2 only ----
    #pragma unroll
    for (int q = 0; q < 3; q++) {
        float cb = g[32 + q * 2 + 0];
        float sb = g[32 + q * 2 + 1];
        float ar =  cb * c[q];
        float ai =  sb * s[q];
        float br = -sb * c[q];
        float bi = -cb * s[q];
        int bit = 8 >> q;
        #pragma unroll
        for (int n0 = 0; n0 < 16; n0++) {
            if (n0 & bit) continue;
            int n1 = n0 | bit;
            C2 a0 = st[n0], a1 = st[n1];
            st[n0].r =  ar * a0.r - ai * a0.i + br * a1.r - bi * a1.i;
            st[n0].i =  ar * a0.i + ai * a0.r + br * a1.i + bi * a1.r;
            st[n1].r = -br * a0.r - bi * a0.i + ar * a1.r + ai * a1.i;
            st[n1].i = -br * a0.i + bi * a0.r + ar * a1.i - ai * a1.r;
        }
    }

    // ---- qubit-3 M-operator fold: S/D per q3-pair ----
    float m_coef, cu, cv;
    {
        float cs2 = __builtin_fmaf(-s[3], s[3], c[3] * c[3]);  // cos(x3)
        m_coef = g[40] * cs2;
        cu = g[41];
        cv = g[42] * (c[3] * s[3]);
    }

    float S[8], D[8];
    #pragma unroll
    for (int m = 0; m < 8; m++) {
        C2 a0 = st[2 * m], a1 = st[2 * m + 1];
        float q0 = __builtin_fmaf(a0.i, a0.i, a0.r * a0.r);
        float q1 = __builtin_fmaf(a1.i, a1.i, a1.r * a1.r);
        float Rc = __builtin_fmaf(a0.i, a1.i, a0.r * a1.r);
        float Ic = __builtin_fmaf(-a0.i, a1.r, a0.r * a1.i);
        S[m] = q0 + q1;
        float dd = q0 - q1;
        float Dm = m_coef * dd;
        Dm = __builtin_fmaf(cu, Rc, Dm);
        Dm = __builtin_fmaf(cv, Ic, Dm);
        D[m] = Dm;
    }

    // signs: m = (i0,i1,i2); z0:(-1)^i0  z1:(-1)^(i0+i1)  z2,z3:(-1)^(i0+i1+i2)
    float e0 = S[0] + S[1], e1 = S[2] + S[3], e2 = S[4] + S[5], e3 = S[6] + S[7];
    float z0 = (e0 + e1) - (e2 + e3);
    float z1 = (e0 - e1) - (e2 - e3);
    float f0 = S[0] - S[1], f1 = S[2] - S[3], f2 = S[4] - S[5], f3 = S[6] - S[7];
    float z2 = (f0 - f1) - (f2 - f3);
    float g0 = D[0] - D[1], g1 = D[2] - D[3], g2 = D[4] - D[5], g3 = D[6] - D[7];
    float z3 = (g0 - g1) - (g2 - g3);

    return make_float4(z0, z1, z2, z3);
}

__global__ void __launch_bounds__(256) qml_kernel(
        const float* __restrict__ x, const float* __restrict__ g,
        float* __restrict__ out, int batch, int stride) {
    int tid = blockIdx.x * blockDim.x + threadIdx.x;
    if (tid >= stride) return;

    const float4* __restrict__ x4 = reinterpret_cast<const float4*>(x);
    float4* __restrict__ o4 = reinterpret_cast<float4*>(out);

    int last = batch - 1;
    int i0 = tid;
    int i1 = min(tid + stride, last);
    int i2 = min(tid + 2 * stride, last);
    int i3 = min(tid + 3 * stride, last);

    // issue all four input loads back-to-back: one latency exposure
    float4 xa = x4[i0];
    float4 xb = x4[i1];
    float4 xc = x4[i2];
    float4 xd = x4[i3];

    // sequential processing: register lifetimes don't overlap (unlike the
    // failed round-2 interleaved variant), store ends each sample's lifetime
    o4[i0] = sample_out(xa, g);
    o4[i1] = sample_out(xb, g);
    o4[i2] = sample_out(xc, g);
    o4[i3] = sample_out(xd, g);
}

extern "C" void kernel_launch(void* const* d_in, const int* in_sizes, int n_in,
                              void* d_out, int out_size, void* d_ws, size_t ws_size,
                              hipStream_t stream) {
    const float* x = (const float*)d_in[0];      // [B,4]
    const float* w = (const float*)d_in[1];      // [2,4,2]
    float* out = (float*)d_out;                  // [B,4]
    float* g = (float*)d_ws;                     // 44 floats of gate constants
    int batch = in_sizes[0] / 4;

    precompute_gates<<<1, 64, 0, stream>>>(w, g);
    int stride = (batch + 3) / 4;                // samples per k-slot
    int block = 256;
    int grid = (stride + block - 1) / block;     // B=1M -> 1024 blocks
    qml_kernel<<<grid, block, 0, stream>>>(x, g, out, batch, stride);
}

// Round 5
// 94.770 us; speedup vs baseline: 1.0009x; 1.0009x over previous
//
#include <hip/hip_runtime.h>

// 4-qubit, 2-layer QML circuit, B=1M samples, one thread/sample.
// Structure = round-0 champion EXACTLY (1 sample/thread, precompute kernel
// -> SGPR gate table, __sincosf per-sample trig, 256-thread blocks).
// R2/R4 (multi-sample) lose: independent sample bodies get interleaved by
// the compiler -> VGPR blow-up. R1 (per-thread weight trig) loses: trans-pipe
// cost. So only the per-sample instruction count is changed here, via the
// harness-validated algebra from round 3:
//  - layer-2 RZ gates dead (diagonal; killed by final CNOT perm + |.|^2)
//  - layer-2 gate = RY(wy)*RX(x): SU(2), al=(cb*c, sb*s), be=(-sb*c, -cb*s),
//    built with 4 mults (round-0 built 8 complex entries with 16 FMAs)
//  - qubit-3 layer-2 gate folded into the observables:
//    M3 = U3^dag Z U3 = m*Z + u*X + v*Y; m = cos(wy3)cos(x3),
//    u = -sin(wy3), v = cos(wy3)sin(x3). Per q3-pair (a0,a1) after the
//    q0..q2 butterflies: S = |a0|^2+|a1|^2 (unitarity),
//    D = m(|a0|^2-|a1|^2) + 2u Re(a0* a1) + 2v Im(a0* a1);
//    z0..z2 = prefix-parity signed sums of S, z3 = same signed sum of D.
//  Net: ~-170 VALU/sample vs round 0, fewer live registers, same structure.
//
// Flat amp index n = q0*8 + q1*4 + q2*2 + q3 (qubit 0 = bit 3).

struct C2 { float r, i; };

__device__ __forceinline__ C2 cmul(C2 a, C2 b) {
    C2 o;
    o.r = a.r * b.r - a.i * b.i;
    o.i = a.r * b.i + a.i * b.r;
    return o;
}

// ---- precompute weight-only gate constants (44 floats) ----
// g[0..31]:  l=0 qubit q: g[q*8 + 0..7] = Pr,Pi,Qr,Qi,Rr,Ri,Sr,Si
// g[32..37]: l=1 qubit q<3: cos(wy/2), sin(wy/2)
// g[40..42]: l=1 qubit 3 (M-operator): cos(wy3), -2*sin(wy3), 4*cos(wy3)
__global__ void precompute_gates(const float* __restrict__ w, float* __restrict__ g) {
    int t = threadIdx.x;  // 0..7 -> l*4 + q
    if (t >= 8) return;
    int l = t >> 2, q = t & 3;
    if (l == 0) {
        float thy = w[q * 2 + 0];
        float thz = w[q * 2 + 1];
        float cy = cosf(0.5f * thy), sy = sinf(0.5f * thy);
        float cz = cosf(0.5f * thz), sz = sinf(0.5f * thz);
        float* o = g + q * 8;
        // v0 = c*P + s*Q ; v1 = c*R + s*S  (RZ*RY*RX|0>)
        o[0] = cz * cy;  o[1] = -sz * cy;
        o[2] = sz * sy;  o[3] =  cz * sy;
        o[4] = cz * sy;  o[5] =  sz * sy;
        o[6] = sz * cy;  o[7] = -cz * cy;
    } else if (q < 3) {
        float thy = w[8 + q * 2 + 0];  // layer-2 RZ params are dead
        g[32 + q * 2 + 0] = cosf(0.5f * thy);
        g[32 + q * 2 + 1] = sinf(0.5f * thy);
    } else {
        float thy = w[8 + 3 * 2 + 0];  // qubit 3: full-angle M constants
        g[40] =  cosf(thy);
        g[41] = -2.0f * sinf(thy);
        g[42] =  4.0f * cosf(thy);
    }
}

__device__ __forceinline__ void cnot_chain(C2 st[16]) {
    // CNOT(0,1): q0=1 -> flip q1: swap n=8..11 <-> 12..15
    #pragma unroll
    for (int j = 0; j < 4; j++) { C2 t = st[8 + j]; st[8 + j] = st[12 + j]; st[12 + j] = t; }
    // CNOT(1,2): q1=1 -> flip q2
    {
        C2 t;
        t = st[4];  st[4]  = st[6];  st[6]  = t;
        t = st[5];  st[5]  = st[7];  st[7]  = t;
        t = st[12]; st[12] = st[14]; st[14] = t;
        t = st[13]; st[13] = st[15]; st[15] = t;
    }
    // CNOT(2,3): q2=1 -> flip q3
    {
        C2 t;
        t = st[2];  st[2]  = st[3];  st[3]  = t;
        t = st[6];  st[6]  = st[7];  st[7]  = t;
        t = st[10]; st[10] = st[11]; st[11] = t;
        t = st[14]; st[14] = st[15]; st[15] = t;
    }
}

__global__ void __launch_bounds__(256) qml_kernel(
        const float* __restrict__ x, const float* __restrict__ g,
        float* __restrict__ out, int batch) {
    int tid = blockIdx.x * blockDim.x + threadIdx.x;
    if (tid >= batch) return;

    float4 xv = reinterpret_cast<const float4*>(x)[tid];
    float c[4], s[4];
    __sincosf(0.5f * xv.x, &s[0], &c[0]);
    __sincosf(0.5f * xv.y, &s[1], &c[1]);
    __sincosf(0.5f * xv.z, &s[2], &c[2]);
    __sincosf(0.5f * xv.w, &s[3], &c[3]);

    // ---- layer 1: product state, per-qubit 2-vectors (table -> s_loads) ----
    C2 v[4][2];
    #pragma unroll
    for (int q = 0; q < 4; q++) {
        const float* o = g + q * 8;
        v[q][0].r = c[q] * o[0] + s[q] * o[2];
        v[q][0].i = c[q] * o[1] + s[q] * o[3];
        v[q][1].r = c[q] * o[4] + s[q] * o[6];
        v[q][1].i = c[q] * o[5] + s[q] * o[7];
    }

    // ---- tensor expansion to 16 amps ----
    C2 t01[4], t23[4], st[16];
    #pragma unroll
    for (int a = 0; a < 2; a++)
        #pragma unroll
        for (int b = 0; b < 2; b++) {
            t01[a * 2 + b] = cmul(v[0][a], v[1][b]);
            t23[a * 2 + b] = cmul(v[2][a], v[3][b]);
        }
    #pragma unroll
    for (int a = 0; a < 4; a++)
        #pragma unroll
        for (int b = 0; b < 4; b++)
            st[a * 4 + b] = cmul(t01[a], t23[b]);

    cnot_chain(st);

    // ---- layer 2: SU(2) = RY(wy)*RX(x) butterflies, qubits 0..2 only ----
    #pragma unroll
    for (int q = 0; q < 3; q++) {
        float cb = g[32 + q * 2 + 0];
        float sb = g[32 + q * 2 + 1];
        float ar =  cb * c[q];
        float ai =  sb * s[q];
        float br = -sb * c[q];
        float bi = -cb * s[q];
        int bit = 8 >> q;
        #pragma unroll
        for (int n0 = 0; n0 < 16; n0++) {
            if (n0 & bit) continue;
            int n1 = n0 | bit;
            C2 a0 = st[n0], a1 = st[n1];
            st[n0].r =  ar * a0.r - ai * a0.i + br * a1.r - bi * a1.i;
            st[n0].i =  ar * a0.i + ai * a0.r + br * a1.i + bi * a1.r;
            st[n1].r = -br * a0.r - bi * a0.i + ar * a1.r + ai * a1.i;
            st[n1].i = -br * a0.i + bi * a0.r + ar * a1.i - ai * a1.r;
        }
    }

    // ---- qubit-3 M-operator fold: S/D per q3-pair ----
    // m = cos(wy3)*cos(x3); cu = -2 sin(wy3); cv = 4 cos(wy3) * c3*s3
    float m_coef, cu, cv;
    {
        float cs2 = __builtin_fmaf(-s[3], s[3], c[3] * c[3]);  // cos(x3)
        m_coef = g[40] * cs2;
        cu = g[41];
        cv = g[42] * (c[3] * s[3]);
    }

    float S[8], D[8];
    #pragma unroll
    for (int m = 0; m < 8; m++) {
        C2 a0 = st[2 * m], a1 = st[2 * m + 1];
        float q0 = __builtin_fmaf(a0.i, a0.i, a0.r * a0.r);
        float q1 = __builtin_fmaf(a1.i, a1.i, a1.r * a1.r);
        float Rc = __builtin_fmaf(a0.i, a1.i, a0.r * a1.r);
        float Ic = __builtin_fmaf(-a0.i, a1.r, a0.r * a1.i);
        S[m] = q0 + q1;
        float dd = q0 - q1;
        float Dm = m_coef * dd;
        Dm = __builtin_fmaf(cu, Rc, Dm);
        Dm = __builtin_fmaf(cv, Ic, Dm);
        D[m] = Dm;
    }

    // signs: m = (i0,i1,i2); z0:(-1)^i0  z1:(-1)^(i0+i1)  z2,z3:(-1)^(i0+i1+i2)
    float e0 = S[0] + S[1], e1 = S[2] + S[3], e2 = S[4] + S[5], e3 = S[6] + S[7];
    float z0 = (e0 + e1) - (e2 + e3);
    float z1 = (e0 - e1) - (e2 - e3);
    float f0 = S[0] - S[1], f1 = S[2] - S[3], f2 = S[4] - S[5], f3 = S[6] - S[7];
    float z2 = (f0 - f1) - (f2 - f3);
    float g0 = D[0] - D[1], g1 = D[2] - D[3], g2 = D[4] - D[5], g3 = D[6] - D[7];
    float z3 = (g0 - g1) - (g2 - g3);

    reinterpret_cast<float4*>(out)[tid] = make_float4(z0, z1, z2, z3);
}

extern "C" void kernel_launch(void* const* d_in, const int* in_sizes, int n_in,
                              void* d_out, int out_size, void* d_ws, size_t ws_size,
                              hipStream_t stream) {
    const float* x = (const float*)d_in[0];      // [B,4]
    const float* w = (const float*)d_in[1];      // [2,4,2]
    float* out = (float*)d_out;                  // [B,4]
    float* g = (float*)d_ws;                     // 44 floats of gate constants
    int batch = in_sizes[0] / 4;

    precompute_gates<<<1, 64, 0, stream>>>(w, g);
    int block = 256;
    int grid = (batch + block - 1) / block;
    qml_kernel<<<grid, block, 0, stream>>>(x, g, out, batch);
}

// Round 6
// 88.245 us; speedup vs baseline: 1.0749x; 1.0739x over previous
//
#include <hip/hip_runtime.h>

// 4-qubit, 2-layer QML circuit, B=1M samples, one thread/sample.
// HAND-PACKED version of the round-0 champion: every complex amplitude is a
// float2 ext-vector, and all gate arithmetic is expressed as
// splat(scalar) * vec FMA chains with shuffled/negated second operands —
// the exact pattern the AMDGPU backend lowers to v_pk_fma_f32 with free
// op_sel / neg modifiers (2 fp32 FLOPs per issue slot).
//
// Session evidence for this design: R0's fully-regular scalar kernel (86 us,
// x2 reproduced) beat every algebraically-reduced variant (92-95 us, x4
// reproduced) despite those having strictly fewer source FLOPs — scalar
// horizontal reductions broke VOP3P packability. So: keep R0's regular
// structure (all 4 layer-2 butterflies, p[16], tree reduction), pack it
// explicitly, and keep only the RZ-drop (harness-validated in round 2; it
// only changes per-qubit CONSTANTS, preserving butterfly shape):
//   layer-2 RZ gates are dead (diagonal; killed by final CNOT perm + |.|^2)
//   layer-2 gate U = RY(wy)*RX(x) is SU(2): U = [[al, be],[-conj(be), conj(al)]]
//     al = (cb*c, sb*s), be = (-sb*c, -cb*s)
//
// Flat amp index n = q0*8 + q1*4 + q2*2 + q3 (qubit 0 = bit 3).
// Weight-only constants in d_ws (40 floats) via tiny precompute kernel ->
// uniform s_loads -> SGPR pairs (legal VOP3P sources).

typedef float v2f __attribute__((ext_vector_type(2)));

__device__ __forceinline__ v2f splat2(float a) { v2f r; r.x = a; r.y = a; return r; }

__device__ __forceinline__ v2f pfma(float a, v2f b, v2f c) {
    return __builtin_elementwise_fma(splat2(a), b, c);
}

// swneg(a) = {-a.y, a.x}   (multiply-by-i pattern; folds to op_sel+neg)
__device__ __forceinline__ v2f swneg(v2f a) { return __builtin_shufflevector(a, -a, 3, 0); }
// swconj(a) = {a.y, -a.x}
__device__ __forceinline__ v2f swconj(v2f a) { return __builtin_shufflevector(a, -a, 1, 2); }

// complex multiply: a*b = splat(a.re)*b + splat(a.im)*{-b.im, b.re}
__device__ __forceinline__ v2f cmul(v2f a, v2f b) {
    return pfma(a.x, b, splat2(a.y) * swneg(b));
}

// ---- precompute weight-only gate constants (40 floats) ----
// g[0..31]:  l=0 qubit q: g[q*8 + 0..7] = Pr,Pi,Qr,Qi,Rr,Ri,Sr,Si
// g[32..39]: l=1 qubit q: g[32 + q*2 + {0,1}] = cos(wy/2), sin(wy/2)
__global__ void precompute_gates(const float* __restrict__ w, float* __restrict__ g) {
    int t = threadIdx.x;  // 0..7 -> l*4 + q
    if (t >= 8) return;
    int l = t >> 2, q = t & 3;
    if (l == 0) {
        float thy = w[q * 2 + 0];
        float thz = w[q * 2 + 1];
        float cy = cosf(0.5f * thy), sy = sinf(0.5f * thy);
        float cz = cosf(0.5f * thz), sz = sinf(0.5f * thz);
        float* o = g + q * 8;
        // v0 = c*P + s*Q ; v1 = c*R + s*S  (RZ*RY*RX|0>)
        o[0] = cz * cy;  o[1] = -sz * cy;
        o[2] = sz * sy;  o[3] =  cz * sy;
        o[4] = cz * sy;  o[5] =  sz * sy;
        o[6] = sz * cy;  o[7] = -cz * cy;
    } else {
        float thy = w[8 + q * 2 + 0];  // layer-2 RZ params are dead
        g[32 + q * 2 + 0] = cosf(0.5f * thy);
        g[32 + q * 2 + 1] = sinf(0.5f * thy);
    }
}

__device__ __forceinline__ void cnot_chain(v2f st[16]) {
    // CNOT(0,1): q0=1 -> flip q1: swap n=8..11 <-> 12..15
    #pragma unroll
    for (int j = 0; j < 4; j++) { v2f t = st[8 + j]; st[8 + j] = st[12 + j]; st[12 + j] = t; }
    // CNOT(1,2): q1=1 -> flip q2
    {
        v2f t;
        t = st[4];  st[4]  = st[6];  st[6]  = t;
        t = st[5];  st[5]  = st[7];  st[7]  = t;
        t = st[12]; st[12] = st[14]; st[14] = t;
        t = st[13]; st[13] = st[15]; st[15] = t;
    }
    // CNOT(2,3): q2=1 -> flip q3
    {
        v2f t;
        t = st[2];  st[2]  = st[3];  st[3]  = t;
        t = st[6];  st[6]  = st[7];  st[7]  = t;
        t = st[10]; st[10] = st[11]; st[11] = t;
        t = st[14]; st[14] = st[15]; st[15] = t;
    }
}

__global__ void __launch_bounds__(256) qml_kernel(
        const float* __restrict__ x, const float* __restrict__ g,
        float* __restrict__ out, int batch) {
    int tid = blockIdx.x * blockDim.x + threadIdx.x;
    if (tid >= batch) return;

    float4 xv = reinterpret_cast<const float4*>(x)[tid];
    float c[4], s[4];
    __sincosf(0.5f * xv.x, &s[0], &c[0]);
    __sincosf(0.5f * xv.y, &s[1], &c[1]);
    __sincosf(0.5f * xv.z, &s[2], &c[2]);
    __sincosf(0.5f * xv.w, &s[3], &c[3]);

    // ---- layer 1: product state, per-qubit 2-vectors ----
    // gv[q*4 + {0,1,2,3}] = P,Q,R,S as (re,im) pairs (SGPR pairs after s_load)
    const v2f* __restrict__ gv = reinterpret_cast<const v2f*>(g);
    v2f v[4][2];
    #pragma unroll
    for (int q = 0; q < 4; q++) {
        v[q][0] = pfma(c[q], gv[q * 4 + 0], splat2(s[q]) * gv[q * 4 + 1]);
        v[q][1] = pfma(c[q], gv[q * 4 + 2], splat2(s[q]) * gv[q * 4 + 3]);
    }

    // ---- tensor expansion to 16 amps ----
    v2f t01[4], t23[4], st[16];
    #pragma unroll
    for (int a = 0; a < 2; a++)
        #pragma unroll
        for (int b = 0; b < 2; b++) {
            t01[a * 2 + b] = cmul(v[0][a], v[1][b]);
            t23[a * 2 + b] = cmul(v[2][a], v[3][b]);
        }
    #pragma unroll
    for (int a = 0; a < 4; a++)
        #pragma unroll
        for (int b = 0; b < 4; b++)
            st[a * 4 + b] = cmul(t01[a], t23[b]);

    cnot_chain(st);

    // ---- layer 2: SU(2) = RY(wy)*RX(x) butterflies, all 4 qubits ----
    // al = (ar, ai) = (cb*c, sb*s); be = (br, bi) = (-sb*c, -cb*s)
    // n0' = al*a0 + be*a1
    // n1' = -conj(be)*a0 + conj(al)*a1 = (nbr,nbi-form) with nbr=-br, nbi=-bi
    #pragma unroll
    for (int q = 0; q < 4; q++) {
        float cb = g[32 + q * 2 + 0];
        float sb = g[32 + q * 2 + 1];
        float ar  = cb * c[q];
        float ai  = sb * s[q];
        float nbr = sb * c[q];
        float nbi = cb * s[q];
        float br = -nbr, bi = -nbi;
        int bit = 8 >> q;
        #pragma unroll
        for (int n0 = 0; n0 < 16; n0++) {
            if (n0 & bit) continue;
            int n1 = n0 | bit;
            v2f a0 = st[n0], a1 = st[n1];
            v2f a0n = swneg(a0),  a1n = swneg(a1);
            v2f a0c = swconj(a0), a1c = swconj(a1);
            st[n0] = pfma(ar,  a0, pfma(ai,  a0n, pfma(br, a1, splat2(bi) * a1n)));
            st[n1] = pfma(nbr, a0, pfma(nbi, a0c, pfma(ar, a1, splat2(ai) * a1c)));
        }
    }

    cnot_chain(st);

    // ---- probabilities and <Z_i> (R0's tree, packed |.|^2) ----
    float p[16];
    #pragma unroll
    for (int n = 0; n < 16; n++) {
        v2f sq = st[n] * st[n];
        p[n] = sq.x + sq.y;
    }

    float a8[8], z3 = 0.f;
    #pragma unroll
    for (int m = 0; m < 8; m++) { a8[m] = p[2 * m] + p[2 * m + 1]; z3 += p[2 * m] - p[2 * m + 1]; }
    float b4[4], z2 = 0.f;
    #pragma unroll
    for (int k = 0; k < 4; k++) { b4[k] = a8[2 * k] + a8[2 * k + 1]; z2 += a8[2 * k] - a8[2 * k + 1]; }
    float z1 = (b4[0] - b4[1]) + (b4[2] - b4[3]);
    float z0 = (b4[0] + b4[1]) - (b4[2] + b4[3]);

    reinterpret_cast<float4*>(out)[tid] = make_float4(z0, z1, z2, z3);
}

extern "C" void kernel_launch(void* const* d_in, const int* in_sizes, int n_in,
                              void* d_out, int out_size, void* d_ws, size_t ws_size,
                              hipStream_t stream) {
    const float* x = (const float*)d_in[0];      // [B,4]
    const float* w = (const float*)d_in[1];      // [2,4,2]
    float* out = (float*)d_out;                  // [B,4]
    float* g = (float*)d_ws;                     // 40 floats of gate constants
    int batch = in_sizes[0] / 4;

    precompute_gates<<<1, 64, 0, stream>>>(w, g);
    int block = 256;
    int grid = (batch + block - 1) / block;
    qml_kernel<<<grid, block, 0, stream>>>(x, g, out, batch);
}